// Round 5
// baseline (1262.280 us; speedup 1.0000x reference)
//
#include <hip/hip_runtime.h>

// Problem dims
constexpr int Bn = 64;     // batch
constexpr int Dn = 512;    // embed dim
constexpr int Mn = 1024;   // M
constexpr int Ln = 256;    // L
constexpr int Kn = 30;     // K heads

typedef __attribute__((ext_vector_type(4))) float f32x4;

__device__ __forceinline__ f32x4 fma4(float a, f32x4 b, f32x4 c) {
    c.x += a * b.x; c.y += a * b.y; c.z += a * b.z; c.w += a * b.w;
    return c;
}

// ---------------------------------------------------------------------------
// fp32 transpose (for W_b^T): Xt[c][r] = X[r][c], R,C % 32 == 0
// ---------------------------------------------------------------------------
__global__ void transpose_f32_kernel(const float* __restrict__ X,
                                     float* __restrict__ Xt, int R, int C)
{
    __shared__ float tile[32][33];
    const int c0 = blockIdx.x * 32, r0 = blockIdx.y * 32;
    const int tx = threadIdx.x, ty = threadIdx.y;
    #pragma unroll
    for (int i = 0; i < 4; i++)
        tile[ty + 8 * i][tx] = X[(long)(r0 + ty + 8 * i) * C + c0 + tx];
    __syncthreads();
    #pragma unroll
    for (int i = 0; i < 4; i++)
        Xt[(long)(c0 + ty + 8 * i) * R + r0 + tx] = tile[tx][ty + 8 * i];
}

// ---------------------------------------------------------------------------
// kNT: out[b,k,l] = Sum_d A[k,d] * Q[b,l,d]  (A thin [30,512], per-batch via sA)
// LOGITS=false: write raw to outR[b,30,256].
// LOGITS=true:  outS[b,l] = Sum_k w[k]*tanh(addC[b,k,l] + out[k,l]).
// grid (32 lblk, 64 b), block 256 = 4 waves: wave (khalf h, l-quad lg).
// ---------------------------------------------------------------------------
template <bool LOGITS>
__global__ __launch_bounds__(256) void kNT_kernel(
    const float* __restrict__ A, long sA,
    const float* __restrict__ Q,
    const float* __restrict__ addC,
    const float* __restrict__ wvec,
    float* __restrict__ outR,
    float* __restrict__ outS)
{
    __shared__ float as_[30][256];   // 30 KB
    __shared__ float red[30][8];
    __shared__ float wh[30];
    const int lb = blockIdx.x, b = blockIdx.y;
    const int t = threadIdx.x, w = t >> 6, lane = t & 63;
    const int h = w & 1, lg = w >> 1;
    const int l0 = lb * 8 + lg * 4;
    if (LOGITS && t < 30) wh[t] = wvec[t];
    float acc[4][15] = {};
    const float* Ab = A + (long)b * sA;
    for (int dc = 0; dc < 512; dc += 256) {
        __syncthreads();
        for (int idx = t; idx < 30 * 256; idx += 256)
            as_[idx >> 8][idx & 255] = Ab[(long)(idx >> 8) * Dn + dc + (idx & 255)];
        __syncthreads();
        f32x4 q[4];
        #pragma unroll
        for (int ll = 0; ll < 4; ll++)
            q[ll] = *(const f32x4*)(Q + ((long)b * Ln + l0 + ll) * Dn + dc + 4 * lane);
        #pragma unroll
        for (int r = 0; r < 15; r++) {
            f32x4 g4 = *(const f32x4*)&as_[h * 15 + r][4 * lane];
            #pragma unroll
            for (int ll = 0; ll < 4; ll++)
                acc[ll][r] += g4.x * q[ll].x + g4.y * q[ll].y +
                              g4.z * q[ll].z + g4.w * q[ll].w;
        }
    }
    #pragma unroll
    for (int ll = 0; ll < 4; ll++)
        #pragma unroll
        for (int r = 0; r < 15; r++) {
            float a = acc[ll][r];
            #pragma unroll
            for (int off = 32; off > 0; off >>= 1) a += __shfl_down(a, off, 64);
            if (lane == 0) red[h * 15 + r][lg * 4 + ll] = a;
        }
    __syncthreads();
    if (LOGITS) {
        if (t < 8) {
            int l = lb * 8 + t;
            float s = 0.f;
            #pragma unroll
            for (int k = 0; k < 30; k++)
                s += wh[k] * tanhf(addC[((long)b * Kn + k) * Ln + l] + red[k][t]);
            outS[(long)b * Ln + l] = s;
        }
    } else {
        if (t < 240) {
            int k = t >> 3, l = lb * 8 + (t & 7);
            outR[((long)b * Kn + k) * Ln + l] = red[k][t & 7];
        }
    }
}

// ---------------------------------------------------------------------------
// kU: U[b,k,d] = Sum_l WqQ[b,k,l] * Q[b,l,d]
// grid (2 dc, 2 kh, 64 b), block 256: thread owns one d, 15 k-accs.
// ---------------------------------------------------------------------------
__global__ __launch_bounds__(256) void kU_kernel(
    const float* __restrict__ WqQ, const float* __restrict__ Q,
    float* __restrict__ U)
{
    __shared__ float wq[15][256];   // 15 KB
    const int dc = blockIdx.x, kh = blockIdx.y, b = blockIdx.z;
    const int t = threadIdx.x;
    for (int idx = t; idx < 15 * 256; idx += 256)
        wq[idx >> 8][idx & 255] =
            WqQ[((long)b * Kn + kh * 15 + (idx >> 8)) * Ln + (idx & 255)];
    __syncthreads();
    const int d = dc * 256 + t;
    float acc[15] = {};
    const float* Qb = Q + (long)b * Ln * Dn + d;
    for (int l0 = 0; l0 < 256; l0 += 4) {
        float q0 = Qb[(long)(l0 + 0) * Dn];
        float q1 = Qb[(long)(l0 + 1) * Dn];
        float q2 = Qb[(long)(l0 + 2) * Dn];
        float q3 = Qb[(long)(l0 + 3) * Dn];
        #pragma unroll
        for (int r = 0; r < 15; r++) {
            f32x4 w4 = *(const f32x4*)&wq[r][l0];
            acc[r] += w4.x * q0 + w4.y * q1 + w4.z * q2 + w4.w * q3;
        }
    }
    #pragma unroll
    for (int r = 0; r < 15; r++)
        U[((long)b * Kn + kh * 15 + r) * Dn + d] = acc[r];
}

// ---------------------------------------------------------------------------
// kSv: one pass over V[b]: WvV[k,m] = Sum_d W_v[k,d] V[d,m] (k<30, to global),
// Tv[k,m] = Sum_d P[b,k,d] V[d,m] (LDS only), then
// sv[b,m] = Sum_k w_hv[k] * tanh(WvV + Tv).
// grid (4 m-strip, 64 b), block 256 = 4 waves: wave w owns S-rows 15w..15w+14
// (S = [W_v; P[b]], 60 rows). Thread: 4 m per lane (float4).
// ---------------------------------------------------------------------------
__global__ __launch_bounds__(256) void kSv_kernel(
    const float* __restrict__ Wv, const float* __restrict__ P,
    const float* __restrict__ V, const float* __restrict__ whv,
    float* __restrict__ WvV, float* __restrict__ sv)
{
    __shared__ float lds[15360];                       // 61.4 KB
    float (*WvVS)[256] = (float(*)[256])lds;           // [30][256]
    float (*TvS)[256]  = (float(*)[256])(lds + 7680);  // [30][256]
    float (*Sc)[64]    = (float(*)[64])lds;            // [60][64] staging (aliased in time)
    __shared__ float wh[30];
    const int ms = blockIdx.x, b = blockIdx.y;
    const int t = threadIdx.x, w = t >> 6, lane = t & 63;
    const int m0 = ms * 256;
    const int row0 = 15 * w;
    if (t < 30) wh[t] = whv[t];
    f32x4 acc[15];
    #pragma unroll
    for (int r = 0; r < 15; r++) acc[r] = (f32x4){0.f, 0.f, 0.f, 0.f};

    for (int d0 = 0; d0 < 512; d0 += 64) {
        __syncthreads();      // previous iteration's reads of Sc are done
        for (int idx = t; idx < 60 * 64; idx += 256) {
            int r = idx >> 6, dd = idx & 63;
            Sc[r][dd] = (r < 30) ? Wv[(long)r * Dn + d0 + dd]
                                 : P[((long)b * Kn + (r - 30)) * Dn + d0 + dd];
        }
        __syncthreads();
        const float* Vp = V + ((long)b * Dn + d0) * Mn + m0 + 4 * lane;
        #pragma unroll 4
        for (int dd = 0; dd < 64; dd += 4) {
            f32x4 v0 = *(const f32x4*)(Vp + (long)(dd + 0) * Mn);
            f32x4 v1 = *(const f32x4*)(Vp + (long)(dd + 1) * Mn);
            f32x4 v2 = *(const f32x4*)(Vp + (long)(dd + 2) * Mn);
            f32x4 v3 = *(const f32x4*)(Vp + (long)(dd + 3) * Mn);
            #pragma unroll
            for (int r = 0; r < 15; r++) {
                f32x4 s = *(const f32x4*)&Sc[row0 + r][dd];
                acc[r] = fma4(s.x, v0, acc[r]);
                acc[r] = fma4(s.y, v1, acc[r]);
                acc[r] = fma4(s.z, v2, acc[r]);
                acc[r] = fma4(s.w, v3, acc[r]);
            }
        }
    }
    __syncthreads();   // Sc dead; write results into aliased region
    #pragma unroll
    for (int r = 0; r < 15; r++) {
        int k = row0 + r;           // 0..59
        if (k < 30) {
            *(f32x4*)&WvVS[k][4 * lane] = acc[r];
            *(f32x4*)(WvV + ((long)b * Kn + k) * Mn + m0 + 4 * lane) = acc[r];
        } else {
            *(f32x4*)&TvS[k - 30][4 * lane] = acc[r];
        }
    }
    __syncthreads();
    float s = 0.f;
    #pragma unroll
    for (int k = 0; k < 30; k++)
        s += wh[k] * tanhf(WvVS[k][t] + TvS[k][t]);
    sv[(long)b * Mn + m0 + t] = s;
}

// ---------------------------------------------------------------------------
// kR: R[b,k,e] = Sum_m WvV[b,k,m] * V[b,e,m]
// grid (64 eblk, 64 b), block 256 = 4 waves: wave (khalf h, e-quad eg);
// 8 e per block. Lane covers 4 m (float4); butterfly-reduce at end.
// ---------------------------------------------------------------------------
__global__ __launch_bounds__(256) void kR_kernel(
    const float* __restrict__ WvV, const float* __restrict__ V,
    float* __restrict__ R)
{
    __shared__ float ws[30][256];   // 30 KB
    const int eb = blockIdx.x, b = blockIdx.y;
    const int t = threadIdx.x, w = t >> 6, lane = t & 63;
    const int h = w & 1, eg = w >> 1;
    const int e0 = eb * 8 + eg * 4;
    float acc[4][15] = {};
    for (int mc = 0; mc < 1024; mc += 256) {
        __syncthreads();
        for (int idx = t; idx < 30 * 256; idx += 256)
            ws[idx >> 8][idx & 255] =
                WvV[((long)b * Kn + (idx >> 8)) * Mn + mc + (idx & 255)];
        __syncthreads();
        f32x4 v[4];
        #pragma unroll
        for (int ee = 0; ee < 4; ee++)
            v[ee] = *(const f32x4*)(V + ((long)b * Dn + e0 + ee) * Mn + mc + 4 * lane);
        #pragma unroll
        for (int r = 0; r < 15; r++) {
            f32x4 s = *(const f32x4*)&ws[h * 15 + r][4 * lane];
            #pragma unroll
            for (int ee = 0; ee < 4; ee++)
                acc[ee][r] += s.x * v[ee].x + s.y * v[ee].y +
                              s.z * v[ee].z + s.w * v[ee].w;
        }
    }
    #pragma unroll
    for (int ee = 0; ee < 4; ee++)
        #pragma unroll
        for (int r = 0; r < 15; r++) {
            float a = acc[ee][r];
            #pragma unroll
            for (int off = 32; off > 0; off >>= 1) a += __shfl_down(a, off, 64);
            if (lane == 0)
                R[((long)b * Kn + h * 15 + r) * Dn + e0 + ee] = a;
        }
}

// ---------------------------------------------------------------------------
// fp32 tiled SGEMM (full tiles): C[M,N] = A[M,K]*B[K,N]  (used for P and G,
// flattened to [1920,512] @ [512,512])
// ---------------------------------------------------------------------------
__global__ __launch_bounds__(256) void sgemm_kernel(
    const float* __restrict__ A, const float* __restrict__ B,
    float* __restrict__ Cout, int Mdim, int Ndim, int Kdim)
{
    constexpr int BM = 64, BN = 64, BK = 16;
    __shared__ float As[BK][BM + 1];
    __shared__ float Bs[BK][BN + 1];

    const int tid = threadIdx.x;
    const int tx = tid & 15;
    const int ty = tid >> 4;
    const int row0 = blockIdx.y * BM + ty * 4;
    const int col0 = blockIdx.x * BN + tx * 4;

    float acc[4][4] = {};

    for (int k0 = 0; k0 < Kdim; k0 += BK) {
        #pragma unroll
        for (int i = 0; i < 4; i++) {
            int idx = tid + i * 256;
            int m  = idx >> 4;
            int kk = idx & 15;
            As[kk][m] = A[(long)(blockIdx.y * BM + m) * Kdim + (k0 + kk)];
        }
        #pragma unroll
        for (int i = 0; i < 4; i++) {
            int idx = tid + i * 256;
            int kk = idx >> 6;
            int n  = idx & 63;
            Bs[kk][n] = B[(long)(k0 + kk) * Ndim + (blockIdx.x * BN + n)];
        }
        __syncthreads();
        #pragma unroll
        for (int kk = 0; kk < BK; kk++) {
            float a[4], bb[4];
            #pragma unroll
            for (int i = 0; i < 4; i++) a[i] = As[kk][ty * 4 + i];
            #pragma unroll
            for (int j = 0; j < 4; j++) bb[j] = Bs[kk][tx * 4 + j];
            #pragma unroll
            for (int i = 0; i < 4; i++)
                #pragma unroll
                for (int j = 0; j < 4; j++)
                    acc[i][j] += a[i] * bb[j];
        }
        __syncthreads();
    }

    #pragma unroll
    for (int i = 0; i < 4; i++)
        #pragma unroll
        for (int j = 0; j < 4; j++)
            Cout[(long)(row0 + i) * Ndim + col0 + j] = acc[i][j];
}

// ---------------------------------------------------------------------------
// pure softmax over precomputed logits s[b][COLS] -> a[b][COLS]
// ---------------------------------------------------------------------------
template <int COLS>
__global__ void softmax2_kernel(const float* __restrict__ s, float* __restrict__ a)
{
    const int b = blockIdx.x;
    const int m = threadIdx.x;
    float x = s[(long)b * COLS + m];

    __shared__ float red[COLS / 64];
    __shared__ float bcastv;
    const int wid = m >> 6, lane = m & 63;

    float v = x;
    #pragma unroll
    for (int off = 32; off > 0; off >>= 1) v = fmaxf(v, __shfl_down(v, off, 64));
    if (lane == 0) red[wid] = v;
    __syncthreads();
    if (m == 0) {
        float mx = red[0];
        for (int i = 1; i < COLS / 64; i++) mx = fmaxf(mx, red[i]);
        bcastv = mx;
    }
    __syncthreads();
    const float e = expf(x - bcastv);
    v = e;
    #pragma unroll
    for (int off = 32; off > 0; off >>= 1) v += __shfl_down(v, off, 64);
    if (lane == 0) red[wid] = v;
    __syncthreads();
    if (m == 0) {
        float sm = 0.f;
        for (int i = 0; i < COLS / 64; i++) sm += red[i];
        bcastv = sm;
    }
    __syncthreads();
    a[(long)b * COLS + m] = e / bcastv;
}

// ---------------------------------------------------------------------------
// v1[b,e] = Sum_m a_v[b,m] * V[b,e,m]   (wave per (b,e))
// ---------------------------------------------------------------------------
__global__ __launch_bounds__(64) void poolv_kernel(
    const float* __restrict__ a_v, const float* __restrict__ V,
    float* __restrict__ v1)
{
    const int e = blockIdx.x, b = blockIdx.y;
    const int lane = threadIdx.x;
    const float* vrow = V + ((long)b * Dn + e) * Mn;
    const float* av = a_v + (long)b * Mn;
    float acc = 0.f;
    #pragma unroll
    for (int i = 0; i < 16; i++) acc += vrow[lane + i * 64] * av[lane + i * 64];
    #pragma unroll
    for (int off = 32; off > 0; off >>= 1) acc += __shfl_down(acc, off, 64);
    if (lane == 0) v1[(long)b * Dn + e] = acc;
}

// ---------------------------------------------------------------------------
// q1[b,e] = Sum_l a_q[b,l] * Q[b,l,e]
// ---------------------------------------------------------------------------
__global__ __launch_bounds__(512) void poolq_kernel(
    const float* __restrict__ a_q, const float* __restrict__ Q,
    float* __restrict__ q1)
{
    const int b = blockIdx.x, e = threadIdx.x;
    const float* aq = a_q + (long)b * Ln;
    float acc = 0.f;
    for (int l = 0; l < Ln; l++) acc += aq[l] * Q[((long)b * Ln + l) * Dn + e];
    q1[(long)b * Dn + e] = acc;
}

// ---------------------------------------------------------------------------
// Broadcast outputs: out_v[b,m,e] = v1[b,e]; out_q[b,l,e] = q1[b,e]
// ---------------------------------------------------------------------------
__global__ void bcast_kernel(const float* __restrict__ v1,
                             const float* __restrict__ q1,
                             float* __restrict__ out)
{
    const long nv4 = (long)Bn * Mn * Dn / 4;
    const long nq4 = (long)Bn * Ln * Dn / 4;
    long idx = (long)blockIdx.x * blockDim.x + threadIdx.x;
    float4* o4 = (float4*)out;
    if (idx < nv4) {
        long fidx = idx * 4;
        int e4 = (int)(fidx & (Dn - 1));
        long bm = fidx >> 9;
        int b = (int)(bm >> 10);
        o4[idx] = *(const float4*)(v1 + (long)b * Dn + e4);
    } else if (idx < nv4 + nq4) {
        long fidx = (idx - nv4) * 4;
        int e4 = (int)(fidx & (Dn - 1));
        long bl = fidx >> 9;
        int b = (int)(bl >> 8);
        o4[idx] = *(const float4*)(q1 + (long)b * Dn + e4);
    }
}

// ---------------------------------------------------------------------------

extern "C" void kernel_launch(void* const* d_in, const int* in_sizes, int n_in,
                              void* d_out, int out_size, void* d_ws, size_t ws_size,
                              hipStream_t stream)
{
    const float* V    = (const float*)d_in[0];  // [B, d, M]
    const float* Q    = (const float*)d_in[1];  // [B, L, d]
    const float* W_b  = (const float*)d_in[2];  // [d, d]
    const float* W_v  = (const float*)d_in[3];  // [K, d]
    const float* W_q  = (const float*)d_in[4];  // [K, d]
    const float* w_hv = (const float*)d_in[5];  // [K, 1]
    const float* w_hq = (const float*)d_in[6];  // [K, 1]
    float* out = (float*)d_out;

    // Workspace carve-up (all fp32, ~27.5 MB total)
    float* ws  = (float*)d_ws;
    float* WbT = ws;                            // [512,512]
    float* WqQ = WbT + (long)Dn * Dn;           // [B,30,256]
    float* U   = WqQ + (long)Bn * Kn * Ln;      // [B,30,512]
    float* P   = U   + (long)Bn * Kn * Dn;      // [B,30,512]
    float* WvV = P   + (long)Bn * Kn * Dn;      // [B,30,1024]
    float* R   = WvV + (long)Bn * Kn * Mn;      // [B,30,512]
    float* G   = R   + (long)Bn * Kn * Dn;      // [B,30,512]
    float* sv  = G   + (long)Bn * Kn * Dn;      // [B,1024]
    float* sq  = sv  + (long)Bn * Mn;           // [B,256]
    float* a_v = sq  + (long)Bn * Ln;           // [B,1024]
    float* a_q = a_v + (long)Bn * Mn;           // [B,256]
    float* v1  = a_q + (long)Bn * Ln;           // [B,512]
    float* q1  = v1  + (long)Bn * Dn;           // [B,512]

    // 0. WbT = W_b^T
    transpose_f32_kernel<<<dim3(Dn / 32, Dn / 32), dim3(32, 8), 0, stream>>>(
        W_b, WbT, Dn, Dn);

    // 1. WqQ[b,k,l] = Sum_d W_q[k,d] Q[b,l,d]
    kNT_kernel<false><<<dim3(Ln / 8, Bn), 256, 0, stream>>>(
        W_q, 0, Q, nullptr, nullptr, WqQ, nullptr);

    // 2. U[b] = WqQ[b] @ Q[b]
    kU_kernel<<<dim3(2, 2, Bn), 256, 0, stream>>>(WqQ, Q, U);

    // 3. P = Uflat @ W_b : [1920,512] x [512,512]
    sgemm_kernel<<<dim3(Dn / 64, Bn * Kn / 64), 256, 0, stream>>>(
        U, W_b, P, Bn * Kn, Dn, Dn);

    // 4. Fused: WvV[b] = W_v @ V[b]; sv[b,m] = Sum_k w_hv[k] tanh(WvV + P@V)
    kSv_kernel<<<dim3(Mn / 256, Bn), 256, 0, stream>>>(
        W_v, P, V, w_hv, WvV, sv);

    // 5. R[b] = WvV[b] @ V[b]^T
    kR_kernel<<<dim3(Dn / 8, Bn), 256, 0, stream>>>(WvV, V, R);

    // 6. G = Rflat @ W_b^T : [1920,512] x [512,512]
    sgemm_kernel<<<dim3(Dn / 64, Bn * Kn / 64), 256, 0, stream>>>(
        R, WbT, G, Bn * Kn, Dn, Dn);

    // 7. sq[b,l] = Sum_k w_hq[k] tanh(WqQ[b,k,l] + Sum_d G[b,k,d] Q[b,l,d])
    kNT_kernel<true><<<dim3(Ln / 8, Bn), 256, 0, stream>>>(
        G, (long)Kn * Dn, Q, WqQ, w_hq, nullptr, sq);

    // 8. softmaxes
    softmax2_kernel<Mn><<<Bn, Mn, 0, stream>>>(sv, a_v);
    softmax2_kernel<Ln><<<Bn, Ln, 0, stream>>>(sq, a_q);

    // 9. pooling
    poolv_kernel<<<dim3(Dn, Bn), 64, 0, stream>>>(a_v, V, v1);
    poolq_kernel<<<Bn, Dn, 0, stream>>>(a_q, Q, q1);

    // 10. broadcast outputs
    {
        long n4 = (long)Bn * Mn * Dn / 4 + (long)Bn * Ln * Dn / 4;
        bcast_kernel<<<(int)((n4 + 255) / 256), 256, 0, stream>>>(v1, q1, out);
    }
}

// Round 6
// 635.574 us; speedup vs baseline: 1.9860x; 1.9860x over previous
//
#include <hip/hip_runtime.h>

// Problem dims
constexpr int Bn = 64;     // batch
constexpr int Dn = 512;    // embed dim
constexpr int Mn = 1024;   // M
constexpr int Ln = 256;    // L
constexpr int Kn = 30;     // K heads
constexpr int KP = 32;     // K padded to 32 rows

typedef __attribute__((ext_vector_type(4))) float f32x4;

// ---------------------------------------------------------------------------
// thin GEMM: C[ks][b][Mpad][N](slab) = A[b][M,K] * B  with
//   NN (BT=false): B[b][K,N] row-major (row stride = Ndim)
//   NT (BT=true):  B[b][N,K] row-major (row stride = Kdim)
// A row stride = Kdim (true for every use here). BM=32, BN=128, BK=32,
// 256 threads, acc 4x4 per thread, no cross-lane reductions.
// grid: (N/128, mblocks*KS, Bn). A rows >= Mreal read as 0.
// ---------------------------------------------------------------------------
template <bool BT>
__global__ __launch_bounds__(256) void thin_gemm_kernel(
    const float* __restrict__ A, const float* __restrict__ B,
    float* __restrict__ C,
    int Mreal, int Ndim, int Kdim, int KS,
    long sA, long sB, long sC, long slabC)
{
    constexpr int BM = 32, BN = 128, BK = 32;
    __shared__ float As[BK][BM + 4];   // As[k][m]
    __shared__ float Bs[BK][BN + 4];   // Bs[k][n]

    const int t  = threadIdx.x;
    const int nb = blockIdx.x;
    const int mb = blockIdx.y / KS, ks = blockIdx.y % KS;
    const int b  = blockIdx.z;
    const int n0 = nb * BN, m0 = mb * BM;
    const int kLen = Kdim / KS;
    const int k00  = ks * kLen;
    const float* Ab = A + (long)b * sA;
    const float* Bb = B + (long)b * sB;
    const int tx = t & 31, ty = t >> 5;

    float acc[4][4] = {};

    for (int k0 = k00; k0 < k00 + kLen; k0 += BK) {
        __syncthreads();
        // stage A (32x32): read coalesced along K, write As[k][m]
        {
            int kk = t & 31;
            #pragma unroll
            for (int i = 0; i < 4; i++) {
                int m = (t >> 5) + 8 * i;
                int gm = m0 + m;
                As[kk][m] = (gm < Mreal) ? Ab[(long)gm * Kdim + k0 + kk] : 0.f;
            }
        }
        // stage B (32x128)
        if (BT) {
            int kk = t & 31;
            #pragma unroll
            for (int i = 0; i < 16; i++) {
                int n = (t >> 5) + 8 * i;
                Bs[kk][n] = Bb[(long)(n0 + n) * Kdim + k0 + kk];
            }
        } else {
            int n = t & 127;
            #pragma unroll
            for (int i = 0; i < 16; i++) {
                int kk = (t >> 7) + 2 * i;
                Bs[kk][n] = Bb[(long)(k0 + kk) * Ndim + n0 + n];
            }
        }
        __syncthreads();
        #pragma unroll
        for (int kk = 0; kk < BK; kk++) {
            f32x4 a4 = *(const f32x4*)&As[kk][ty * 4];
            f32x4 b4 = *(const f32x4*)&Bs[kk][tx * 4];
            #pragma unroll
            for (int i = 0; i < 4; i++)
                #pragma unroll
                for (int j = 0; j < 4; j++)
                    acc[i][j] += a4[i] * b4[j];
        }
    }

    float* Cb = C + (long)ks * slabC + (long)b * sC;
    #pragma unroll
    for (int i = 0; i < 4; i++) {
        f32x4 v = {acc[i][0], acc[i][1], acc[i][2], acc[i][3]};
        *(f32x4*)&Cb[(long)(m0 + ty * 4 + i) * Ndim + n0 + tx * 4] = v;
    }
}

// ---------------------------------------------------------------------------
// reduce KS slabs: out[i] = Sum_s in[s*slab + i], n % 4 == 0
// ---------------------------------------------------------------------------
__global__ void reduce_slabs_kernel(const float* __restrict__ in,
                                    float* __restrict__ out,
                                    long n, int ks, long slab)
{
    long i = ((long)blockIdx.x * blockDim.x + threadIdx.x) * 4;
    if (i < n) {
        f32x4 s = *(const f32x4*)(in + i);
        for (int r = 1; r < ks; r++) {
            f32x4 v = *(const f32x4*)(in + (long)r * slab + i);
            s.x += v.x; s.y += v.y; s.z += v.z; s.w += v.w;
        }
        *(f32x4*)(out + i) = s;
    }
}

// ---------------------------------------------------------------------------
// fp32 transpose (for W_b^T)
// ---------------------------------------------------------------------------
__global__ void transpose_f32_kernel(const float* __restrict__ X,
                                     float* __restrict__ Xt, int R, int C)
{
    __shared__ float tile[32][33];
    const int c0 = blockIdx.x * 32, r0 = blockIdx.y * 32;
    const int tx = threadIdx.x, ty = threadIdx.y;
    #pragma unroll
    for (int i = 0; i < 4; i++)
        tile[ty + 8 * i][tx] = X[(long)(r0 + ty + 8 * i) * C + c0 + tx];
    __syncthreads();
    #pragma unroll
    for (int i = 0; i < 4; i++)
        Xt[(long)(c0 + ty + 8 * i) * R + r0 + tx] = tile[tx][ty + 8 * i];
}

// ---------------------------------------------------------------------------
// Sa[b][64][512]: rows 0-29 = W_v, 30-31 = 0, 32-63 = P[b] rows 0-31
// ---------------------------------------------------------------------------
__global__ void build_sa_kernel(const float* __restrict__ Wv,
                                const float* __restrict__ P,
                                float* __restrict__ Sa)
{
    const int b = blockIdx.x, t = threadIdx.x;
    for (int idx = t; idx < 64 * 512; idx += 256) {
        int row = idx >> 9, col = idx & 511;
        float v;
        if (row < 30)      v = Wv[(long)row * Dn + col];
        else if (row < 32) v = 0.f;
        else               v = P[((long)b * KP + row - 32) * Dn + col];
        Sa[((long)b * 64 + row) * Dn + col] = v;
    }
}

// ---------------------------------------------------------------------------
// sv[b,m] = Sum_k whv[k] * tanh(Sout[b][k][m] + Sout[b][32+k][m])
// ---------------------------------------------------------------------------
__global__ void sv_kernel(const float* __restrict__ Sout,
                          const float* __restrict__ whv,
                          float* __restrict__ sv)
{
    const int mc = blockIdx.x, b = blockIdx.y, t = threadIdx.x;
    const int m = mc * 256 + t;
    const float* Sb = Sout + (long)b * 64 * Mn;
    float s = 0.f;
    #pragma unroll
    for (int k = 0; k < Kn; k++)
        s += whv[k] * tanhf(Sb[(long)k * Mn + m] + Sb[(long)(32 + k) * Mn + m]);
    sv[(long)b * Mn + m] = s;
}

// ---------------------------------------------------------------------------
// sq[b,l] = Sum_k whq[k] * tanh(WqQ[b][k][l] + Tq[b][k][l])
// ---------------------------------------------------------------------------
__global__ void sq_kernel(const float* __restrict__ WqQ,
                          const float* __restrict__ Tq,
                          const float* __restrict__ whq,
                          float* __restrict__ sq)
{
    const int b = blockIdx.x, l = threadIdx.x;
    const float* Wb_ = WqQ + (long)b * KP * Ln;
    const float* Tb  = Tq  + (long)b * KP * Ln;
    float s = 0.f;
    #pragma unroll
    for (int k = 0; k < Kn; k++)
        s += whq[k] * tanhf(Wb_[(long)k * Ln + l] + Tb[(long)k * Ln + l]);
    sq[(long)b * Ln + l] = s;
}

// ---------------------------------------------------------------------------
// fp32 tiled SGEMM (full tiles): C[M,N] = A[M,K]*B[K,N]  (P and G: [2048,512,512])
// ---------------------------------------------------------------------------
__global__ __launch_bounds__(256) void sgemm_kernel(
    const float* __restrict__ A, const float* __restrict__ B,
    float* __restrict__ Cout, int Mdim, int Ndim, int Kdim)
{
    constexpr int BM = 64, BN = 64, BK = 16;
    __shared__ float As[BK][BM + 1];
    __shared__ float Bs[BK][BN + 1];

    const int tid = threadIdx.x;
    const int tx = tid & 15;
    const int ty = tid >> 4;
    const int row0 = blockIdx.y * BM + ty * 4;
    const int col0 = blockIdx.x * BN + tx * 4;

    float acc[4][4] = {};

    for (int k0 = 0; k0 < Kdim; k0 += BK) {
        #pragma unroll
        for (int i = 0; i < 4; i++) {
            int idx = tid + i * 256;
            int m  = idx >> 4;
            int kk = idx & 15;
            As[kk][m] = A[(long)(blockIdx.y * BM + m) * Kdim + (k0 + kk)];
        }
        #pragma unroll
        for (int i = 0; i < 4; i++) {
            int idx = tid + i * 256;
            int kk = idx >> 6;
            int n  = idx & 63;
            Bs[kk][n] = B[(long)(k0 + kk) * Ndim + (blockIdx.x * BN + n)];
        }
        __syncthreads();
        #pragma unroll
        for (int kk = 0; kk < BK; kk++) {
            float a[4], bb[4];
            #pragma unroll
            for (int i = 0; i < 4; i++) a[i] = As[kk][ty * 4 + i];
            #pragma unroll
            for (int j = 0; j < 4; j++) bb[j] = Bs[kk][tx * 4 + j];
            #pragma unroll
            for (int i = 0; i < 4; i++)
                #pragma unroll
                for (int j = 0; j < 4; j++)
                    acc[i][j] += a[i] * bb[j];
        }
        __syncthreads();
    }

    #pragma unroll
    for (int i = 0; i < 4; i++)
        #pragma unroll
        for (int j = 0; j < 4; j++)
            Cout[(long)(row0 + i) * Ndim + col0 + j] = acc[i][j];
}

// ---------------------------------------------------------------------------
// pure softmax over logits s[b][COLS] -> a[b][COLS]
// ---------------------------------------------------------------------------
template <int COLS>
__global__ void softmax2_kernel(const float* __restrict__ s, float* __restrict__ a)
{
    const int b = blockIdx.x;
    const int m = threadIdx.x;
    float x = s[(long)b * COLS + m];

    __shared__ float red[COLS / 64];
    __shared__ float bcastv;
    const int wid = m >> 6, lane = m & 63;

    float v = x;
    #pragma unroll
    for (int off = 32; off > 0; off >>= 1) v = fmaxf(v, __shfl_down(v, off, 64));
    if (lane == 0) red[wid] = v;
    __syncthreads();
    if (m == 0) {
        float mx = red[0];
        for (int i = 1; i < COLS / 64; i++) mx = fmaxf(mx, red[i]);
        bcastv = mx;
    }
    __syncthreads();
    const float e = expf(x - bcastv);
    v = e;
    #pragma unroll
    for (int off = 32; off > 0; off >>= 1) v += __shfl_down(v, off, 64);
    if (lane == 0) red[wid] = v;
    __syncthreads();
    if (m == 0) {
        float sm = 0.f;
        for (int i = 0; i < COLS / 64; i++) sm += red[i];
        bcastv = sm;
    }
    __syncthreads();
    a[(long)b * COLS + m] = e / bcastv;
}

// ---------------------------------------------------------------------------
// v1[b,e] = Sum_m a_v[b,m] * V[b,e,m]   (wave per (b,e))
// ---------------------------------------------------------------------------
__global__ __launch_bounds__(64) void poolv_kernel(
    const float* __restrict__ a_v, const float* __restrict__ V,
    float* __restrict__ v1)
{
    const int e = blockIdx.x, b = blockIdx.y;
    const int lane = threadIdx.x;
    const float* vrow = V + ((long)b * Dn + e) * Mn;
    const float* av = a_v + (long)b * Mn;
    float acc = 0.f;
    #pragma unroll
    for (int i = 0; i < 16; i++) acc += vrow[lane + i * 64] * av[lane + i * 64];
    #pragma unroll
    for (int off = 32; off > 0; off >>= 1) acc += __shfl_down(acc, off, 64);
    if (lane == 0) v1[(long)b * Dn + e] = acc;
}

// ---------------------------------------------------------------------------
// poolq partials: pq[ls][b][e] = Sum_{l in ls-chunk} a_q[b,l] * Q[b,l,e]
// grid (4, Bn), 512 threads
// ---------------------------------------------------------------------------
__global__ __launch_bounds__(512) void poolq_kernel(
    const float* __restrict__ a_q, const float* __restrict__ Q,
    float* __restrict__ pq)
{
    const int ls = blockIdx.x, b = blockIdx.y, e = threadIdx.x;
    const float* aq = a_q + (long)b * Ln;
    float acc = 0.f;
    for (int l = ls * 64; l < ls * 64 + 64; l++)
        acc += aq[l] * Q[((long)b * Ln + l) * Dn + e];
    pq[((long)ls * Bn + b) * Dn + e] = acc;
}

// ---------------------------------------------------------------------------
// Broadcast outputs
// ---------------------------------------------------------------------------
__global__ void bcast_kernel(const float* __restrict__ v1,
                             const float* __restrict__ q1,
                             float* __restrict__ out)
{
    const long nv4 = (long)Bn * Mn * Dn / 4;
    const long nq4 = (long)Bn * Ln * Dn / 4;
    long idx = (long)blockIdx.x * blockDim.x + threadIdx.x;
    float4* o4 = (float4*)out;
    if (idx < nv4) {
        long fidx = idx * 4;
        int e4 = (int)(fidx & (Dn - 1));
        long bm = fidx >> 9;
        int b = (int)(bm >> 10);
        o4[idx] = *(const float4*)(v1 + (long)b * Dn + e4);
    } else if (idx < nv4 + nq4) {
        long fidx = (idx - nv4) * 4;
        int e4 = (int)(fidx & (Dn - 1));
        long bl = fidx >> 9;
        int b = (int)(bl >> 8);
        o4[idx] = *(const float4*)(q1 + (long)b * Dn + e4);
    }
}

// ---------------------------------------------------------------------------

extern "C" void kernel_launch(void* const* d_in, const int* in_sizes, int n_in,
                              void* d_out, int out_size, void* d_ws, size_t ws_size,
                              hipStream_t stream)
{
    const float* V    = (const float*)d_in[0];  // [B, d, M]
    const float* Q    = (const float*)d_in[1];  // [B, L, d]
    const float* W_b  = (const float*)d_in[2];  // [d, d]
    const float* W_v  = (const float*)d_in[3];  // [K, d]
    const float* W_q  = (const float*)d_in[4];  // [K, d]
    const float* w_hv = (const float*)d_in[5];  // [K, 1]
    const float* w_hq = (const float*)d_in[6];  // [K, 1]
    float* out = (float*)d_out;

    // sizes (floats)
    const long szWqQ = (long)Bn * KP * Ln;   // 524288
    const long szU   = (long)Bn * KP * Dn;   // 1048576
    const long szSa  = (long)Bn * 64 * Dn;   // 2097152
    const long szSo  = (long)Bn * 64 * Mn;   // 4194304

    float* ws   = (float*)d_ws;
    float* WbT  = ws;                      // 262144
    float* WqQp = WbT  + 262144;           // 4 * szWqQ
    float* WqQ  = WqQp + 4 * szWqQ;
    float* Up   = WqQ  + szWqQ;            // 2 * szU
    float* U    = Up   + 2 * szU;
    float* P    = U    + szU;              // szU
    float* Sa   = P    + szU;              // szSa
    float* Sout = Sa   + szSa;             // szSo
    float* Rp   = Sout + szSo;             // 2 * szU
    float* R    = Rp   + 2 * szU;          // szU
    float* G    = R    + szU;              // szU
    float* Tqp  = G    + szU;              // 4 * szWqQ
    float* Tq   = Tqp  + 4 * szWqQ;
    float* pq   = Tq   + szWqQ;            // 4 * Bn * Dn = 131072
    float* sv   = pq   + 4L * Bn * Dn;
    float* sq   = sv   + (long)Bn * Mn;
    float* a_v  = sq   + (long)Bn * Ln;
    float* a_q  = a_v  + (long)Bn * Mn;
    float* v1   = a_q  + (long)Bn * Ln;
    float* q1   = v1   + (long)Bn * Dn;

    // 0. WbT = W_b^T
    transpose_f32_kernel<<<dim3(Dn / 32, Dn / 32), dim3(32, 8), 0, stream>>>(
        W_b, WbT, Dn, Dn);

    // 1. WqQ[b,k,l] = Wq @ Q[b]^T : NT, M=30, N=256, K=512, KS=4
    thin_gemm_kernel<true><<<dim3(Ln / 128, 4, Bn), 256, 0, stream>>>(
        W_q, Q, WqQp, Kn, Ln, Dn, 4,
        0, (long)Ln * Dn, (long)KP * Ln, (long)Bn * KP * Ln);
    reduce_slabs_kernel<<<(int)(szWqQ / 4 / 256), 256, 0, stream>>>(
        WqQp, WqQ, szWqQ, 4, szWqQ);

    // 2. U[b] = WqQ[b] @ Q[b] : NN, M=32, N=512, K=256, KS=2
    thin_gemm_kernel<false><<<dim3(Dn / 128, 2, Bn), 256, 0, stream>>>(
        WqQ, Q, Up, KP, Dn, Ln, 2,
        (long)KP * Ln, (long)Ln * Dn, (long)KP * Dn, (long)Bn * KP * Dn);
    reduce_slabs_kernel<<<(int)(szU / 4 / 256), 256, 0, stream>>>(
        Up, U, szU, 2, szU);

    // 3. P = Uflat[2048,512] @ W_b
    sgemm_kernel<<<dim3(Dn / 64, Bn * KP / 64), 256, 0, stream>>>(
        U, W_b, P, Bn * KP, Dn, Dn);

    // 4. Sa = [W_v; 0; P[b]]  (64 rows per b)
    build_sa_kernel<<<Bn, 256, 0, stream>>>(W_v, P, Sa);

    // 5. Sout[b] = Sa[b] @ V[b] : NN, M=64 (2 mblocks), N=1024, K=512, KS=1
    //    rows 0-29 = WvV, rows 32-61 = Tv
    thin_gemm_kernel<false><<<dim3(Mn / 128, 2, Bn), 256, 0, stream>>>(
        Sa, V, Sout, 64, Mn, Dn, 1,
        (long)64 * Dn, (long)Dn * Mn, (long)64 * Mn, 0);

    // 6. sv[b,m] = Sum_k whv[k] tanh(WvV + Tv)
    sv_kernel<<<dim3(Mn / 256, Bn), 256, 0, stream>>>(Sout, w_hv, sv);

    // 7. R[b,k,e] = Sum_m WvV[k,m] V[e,m] : NT, A=Sout rows 0-31, N=512, K=1024, KS=2
    thin_gemm_kernel<true><<<dim3(Dn / 128, 2, Bn), 256, 0, stream>>>(
        Sout, V, Rp, KP, Dn, Mn, 2,
        (long)64 * Mn, (long)Dn * Mn, (long)KP * Dn, (long)Bn * KP * Dn);
    reduce_slabs_kernel<<<(int)(szU / 4 / 256), 256, 0, stream>>>(
        Rp, R, szU, 2, szU);

    // 8. G = Rflat[2048,512] @ WbT
    sgemm_kernel<<<dim3(Dn / 64, Bn * KP / 64), 256, 0, stream>>>(
        R, WbT, G, Bn * KP, Dn, Dn);

    // 9. Tq[b,k,l] = Sum_e G[k,e] Q[l,e] : NT, N=256, K=512, KS=4
    thin_gemm_kernel<true><<<dim3(Ln / 128, 4, Bn), 256, 0, stream>>>(
        G, Q, Tqp, KP, Ln, Dn, 4,
        (long)KP * Dn, (long)Ln * Dn, (long)KP * Ln, (long)Bn * KP * Ln);
    reduce_slabs_kernel<<<(int)(szWqQ / 4 / 256), 256, 0, stream>>>(
        Tqp, Tq, szWqQ, 4, szWqQ);

    // 10. sq[b,l] = Sum_k whq[k] tanh(WqQ + Tq)
    sq_kernel<<<Bn, Ln, 0, stream>>>(WqQ, Tq, w_hq, sq);

    // 11. softmaxes
    softmax2_kernel<Mn><<<Bn, Mn, 0, stream>>>(sv, a_v);
    softmax2_kernel<Ln><<<Bn, Ln, 0, stream>>>(sq, a_q);

    // 12. pooling
    poolv_kernel<<<dim3(Dn, Bn), 64, 0, stream>>>(a_v, V, v1);
    poolq_kernel<<<dim3(4, Bn), Dn, 0, stream>>>(a_q, Q, pq);
    reduce_slabs_kernel<<<(int)((long)Bn * Dn / 4 / 256), 256, 0, stream>>>(
        pq, q1, (long)Bn * Dn, 4, (long)Bn * Dn);

    // 13. broadcast outputs
    {
        long n4 = (long)Bn * Mn * Dn / 4 + (long)Bn * Ln * Dn / 4;
        bcast_kernel<<<(int)((n4 + 255) / 256), 256, 0, stream>>>(v1, q1, out);
    }
}